// Round 9
// baseline (879.281 us; speedup 1.0000x reference)
//
#include <hip/hip_runtime.h>

// Soft-DTW (gamma=1), batched 64 x (1024 vs 1024, 2-D points).
// 32 blocks x 1024 threads; each block runs TWO batches (A = 2*bid, B = +1)
// as two independent interleaved chains per thread. Thread t = DP row t.
//
// === Exp-domain recurrence, FP64 state, PER-WAVE offset (R8, verified) ===
//   Z = 2^(off - R*log2e)  =>  Z_d[i] = 2^(-D*log2e) * (Zdiag + Zup + Zleft)
// Chain per step per batch: add+add+mul (f64) + DPP + select; zero
// transcendentals on-chain. k2 = 2^(-cost*log2e) factors computed per epoch
// off-chain. Per-wave power-of-2 rescale each epoch keeps fp64 exponent in
// range (fp64's ~2046-bit window >> the ~400-bit within-wave R-spread).
//
// === R9 changes (perf only; per-batch numerics BIT-IDENTICAL to R8) ===
// Cross-round data: VALU issue is ~93 SIMD-cyc/step in EVERY version while
// wall is ~500-630 => ~80% stall that 4 waves/SIMD don't hide; the softmin
// spine is NOT the limiter (R0 spine ~575cyc vs R8 ~40cyc moved wall only
// 627->504). Remaining per-epoch serial suspects: the shfl_xor exponent
// reduce = 6 DEPENDENT ds_swizzle ops (LDS pipe, ~120cyc each, 16 waves
// contending) + ring lgkm + barrier.
//  1. DPP max-reduce replaces shfl_xor: row_shr:1/2/4/8 + row_bcast15/31 +
//     v_readlane(63). Pure VALU (~6 ops), zero LDS, same max => bit-equal.
//  2. Dual-batch per block: two independent chains/thread double the
//     latency-hiding and per-wave ILP. Registers held ~<=110 so the 16-wave
//     block keeps 4 waves/SIMD: cw[] and wb[] arrays eliminated (k2 computed
//     at epoch bottom; ring written per-step by lane 63).
//
// Skew/ring/epoch protocol (verified R2/R3/R8, unchanged): wave w runs K=8
// diags behind wave w-1; at epoch g step k it is at dk=8g+k+2-8w and reads
// ring[w-1][(g^1)&1][k], written by wave w-1 at its epoch g-1 for the SAME
// dk (one barrier between write and read; overwrite two barriers later).
// One __syncthreads per epoch. Inactive cells: k2=0 -> zn=0 == exp(-INF).
// Final cell snapshotted to (res,res_off) at its own step (exact; rescales
// are powers of 2). R = (res_off - log2(res)) * ln2.

#define N 1024
#define TPB 1024
#define NWAVES (TPB / 64)                      // 16
#define K 8                                    // diagonals per epoch
#define TOTAL (2 * N - 3 + (NWAVES - 1) * K)   // 2045 + 120 = 2165 steps
#define NGRP ((TOTAL + K - 1) / K)             // 271 epochs
#define L2E 1.442695040888963f
#define LN2D 0.6931471805599453

__device__ __forceinline__ float sqdist2(float2 a, float2 b) {
    float dx = a.x - b.x;
    float dy = a.y - b.y;
    return dx * dx + dy * dy;
}

// 64-bit DPP move (two 32-bit halves, same lane pattern; invalid lanes -> 0).
template <int CTRL>
__device__ __forceinline__ double dpp_movd(double src) {
    long long s = __double_as_longlong(src);
    int lo = __builtin_amdgcn_update_dpp(0, (int)(s & 0xffffffffLL),
                                         CTRL, 0xF, 0xF, false);
    int hi = __builtin_amdgcn_update_dpp(0, (int)(s >> 32),
                                         CTRL, 0xF, 0xF, false);
    return __longlong_as_double(((long long)hi << 32) | (unsigned int)lo);
}

// One DPP step of a wave-max reduction (nonneg ints; invalid lanes give 0).
template <int CTRL>
__device__ __forceinline__ int dpp_maxstep(int x) {
    int s = __builtin_amdgcn_update_dpp(0, x, CTRL, 0xF, 0xF, false);
    return max(x, s);
}

// Full 64-lane max of a nonneg int, pure VALU (no LDS), result uniform.
// row_shr 1/2/4/8 builds per-16-row max at lanes 15/31/47/63; bcast15 merges
// row->next-row (lane31 = max 0..31, lane63 = max 32..63); bcast31 merges
// halves (lane63 = max 0..63); readlane broadcasts.
__device__ __forceinline__ int wave_max_i(int x) {
    x = dpp_maxstep<0x111>(x);   // row_shr:1
    x = dpp_maxstep<0x112>(x);   // row_shr:2
    x = dpp_maxstep<0x114>(x);   // row_shr:4
    x = dpp_maxstep<0x118>(x);   // row_shr:8
    x = dpp_maxstep<0x142>(x);   // row_bcast15
    x = dpp_maxstep<0x143>(x);   // row_bcast31
    return __builtin_amdgcn_readlane(x, 63);
}

// exact 2^s as double for s in [-1022, 1023]
__device__ __forceinline__ double pow2d(int s) {
    return __longlong_as_double((long long)(1023 + s) << 52);
}

// k2[k] = act ? 2^(-cost*log2e) : 0 for the K diagonals starting at d0.
// Off-chain: depends only on inputs; called at epoch bottom for next epoch.
__device__ __forceinline__ void compute_k2(
    int d0, int t, float2 spA, const float2* cgA,
    float2 spB, const float2* cgB, double* k2A, double* k2B)
{
    #pragma unroll
    for (int k = 0; k < K; ++k) {
        const int dk = d0 + k;
        const unsigned u = (unsigned)(dk - t);
        const bool act = u < (unsigned)N;
        const unsigned ci = u & (N - 1);    // wrapped -> in-bounds garbage
        float2 cA = cgA[ci];
        float2 cB = cgB[ci];
        float dxA = spA.x - cA.x, dyA = spA.y - cA.y;
        float dxB = spB.x - cB.x, dyB = spB.y - cB.y;
        float eA = __builtin_amdgcn_exp2f((dxA * dxA + dyA * dyA) * (-L2E));
        float eB = __builtin_amdgcn_exp2f((dxB * dxB + dyB * dyB) * (-L2E));
        k2A[k] = act ? (double)eA : 0.0;
        k2B[k] = act ? (double)eB : 0.0;
    }
}

__global__ __launch_bounds__(TPB) void dtw_kernel(
    const float2* __restrict__ snake,
    const float2* __restrict__ contour,
    float* __restrict__ out)
{
    const int t = threadIdx.x;
    const int lane = t & 63;
    const int w = t >> 6;

    __shared__ double ringv[2][NWAVES][2][K];  // [batch][wave][parity][k]
    __shared__ int    ringo[2][NWAVES][2];     // writer's (pre-rescale) off
    __shared__ float  initvals[2][3];          // R0[0], R1[0], R1[1] per batch

    const int bA = 2 * blockIdx.x;
    const float2* sgA = snake   + (size_t)bA * N;
    const float2* cgA = contour + (size_t)bA * N;
    const float2* sgB = snake   + (size_t)(bA + 1) * N;
    const float2* cgB = contour + (size_t)(bA + 1) * N;

    const float2 spA = sgA[t];             // snake points: register-resident
    const float2 spB = sgB[t];

    if (t < 2 * NWAVES * 2 * K) ((double*)ringv)[t] = 0.0;  // Z(INF) = 0
    if (t < 2 * NWAVES * 2)     ((int*)ringo)[t] = 0;
    if (t == 0) {
        // Diagonals 0 and 1 (reference `init`), both batches:
        //   R0[0] = D(0,0);  R1[0] = D(0,1)+D(0,0);  R1[1] = D(1,0)+D(0,0)
        {
            float2 s0 = sgA[0], s1 = sgA[1], c0 = cgA[0], c1 = cgA[1];
            float d00 = sqdist2(s0, c0);
            initvals[0][0] = d00;
            initvals[0][1] = sqdist2(s0, c1) + d00;
            initvals[0][2] = sqdist2(s1, c0) + d00;
        }
        {
            float2 s0 = sgB[0], s1 = sgB[1], c0 = cgB[0], c1 = cgB[1];
            float d00 = sqdist2(s0, c0);
            initvals[1][0] = d00;
            initvals[1][1] = sqdist2(s0, c1) + d00;
            initvals[1][2] = sqdist2(s1, c0) + d00;
        }
    }
    __syncthreads();

    // Z-state entering the wave's first executed step (wave off = 0):
    //   cur = Z_{d-1}[t], nb1 = Z_{d-1}[t-1], nb2 = Z_{d-2}[t-1]
    double curA = 0.0, nb1A = 0.0, nb2A = 0.0;
    double curB = 0.0, nb1B = 0.0, nb2B = 0.0;
    int offA = 0, offB = 0;
    bool adopted = (w == 0);               // wave 0 has no upstream offset
    if (t == 0) {
        curA = (double)__builtin_amdgcn_exp2f(-L2E * initvals[0][1]);
        curB = (double)__builtin_amdgcn_exp2f(-L2E * initvals[1][1]);
    } else if (t == 1) {
        curA = (double)__builtin_amdgcn_exp2f(-L2E * initvals[0][2]);
        nb1A = (double)__builtin_amdgcn_exp2f(-L2E * initvals[0][1]);
        nb2A = (double)__builtin_amdgcn_exp2f(-L2E * initvals[0][0]);
        curB = (double)__builtin_amdgcn_exp2f(-L2E * initvals[1][2]);
        nb1B = (double)__builtin_amdgcn_exp2f(-L2E * initvals[1][1]);
        nb2B = (double)__builtin_amdgcn_exp2f(-L2E * initvals[1][0]);
    } else if (t == 2) {
        nb1A = (double)__builtin_amdgcn_exp2f(-L2E * initvals[0][2]);
        nb1B = (double)__builtin_amdgcn_exp2f(-L2E * initvals[1][2]);
    }

    double resA = 1.0, resB = 1.0;         // final-cell snapshots (t's row)
    int res_offA = 0, res_offB = 0;

    const int lo = (w == 0) ? 2 : (64 * w - 1);  // -1 pre-step seeds nb1
    const int hi = 64 * w + 63 + (N - 1);        // 64w + 1086
    int d0 = 2 - K * w;                          // diag of step k=0, epoch 0

    double k2A[K], k2B[K];                       // step factors (off-chain)
    double rvcA[K], rvcB[K];                     // converted ring (lane 0)
    #pragma unroll
    for (int k = 0; k < K; ++k) { rvcA[k] = 0.0; rvcB[k] = 0.0; }

    compute_k2(d0, t, spA, cgA, spB, cgB, k2A, k2B);  // epoch 0

    for (int g = 0; g < NGRP; ++g) {
        const bool overlap = (d0 <= hi) && (d0 + (K - 1) >= lo);
        if (overlap) {
            // Epoch-start: ring read + conversion to my offset (off-chain).
            if (w > 0) {
                const int p = (g ^ 1) & 1;
                int oinA = ringo[0][w - 1][p];         // wave-uniform
                int oinB = ringo[1][w - 1][p];
                if (!adopted) { offA = oinA; offB = oinB; adopted = true; }
                if (lane == 0) {
                    {
                        int dl = offA - oinA;
                        int c1 = min(max(dl, -1022), 1022);
                        int c2 = min(max(dl - c1, -1022), 1022);
                        double f1 = pow2d(c1), f2 = pow2d(c2);
                        const double* q = &ringv[0][w - 1][p][0];
                        #pragma unroll
                        for (int k = 0; k < K; ++k)
                            rvcA[k] = (q[k] * f1) * f2;
                    }
                    {
                        int dl = offB - oinB;
                        int c1 = min(max(dl, -1022), 1022);
                        int c2 = min(max(dl - c1, -1022), 1022);
                        double f1 = pow2d(c1), f2 = pow2d(c2);
                        const double* q = &ringv[1][w - 1][p][0];
                        #pragma unroll
                        for (int k = 0; k < K; ++k)
                            rvcB[k] = (q[k] * f1) * f2;
                    }
                }
            }

            const int kres = (t + N - 1) - d0;   // step index of my last cell

            // Two independent chains, interleaved (ILP x2):
            // add+add+mul (f64) + DPP + selects per step per batch.
            // Inactive cells: k2=0 -> zn=0 (pre-start/finished lanes stay 0,
            // auto-excluded from the exponent-max rescale).
            #pragma unroll
            for (int k = 0; k < K; ++k) {
                double znA = k2A[k] * ((nb2A + nb1A) + curA);
                double znB = k2B[k] * ((nb2B + nb1B) + curB);
                if (k == kres) {                  // off-spine leaf selects
                    resA = znA; res_offA = offA;
                    resB = znB; res_offB = offB;
                }
                if (lane == 63) {                 // per-step ring write (raw)
                    ringv[0][w][g & 1][k] = znA;
                    ringv[1][w][g & 1][k] = znB;
                }
                curA = znA; curB = znB;
                double aA = dpp_movd<0x111>(znA); // row_shr:1
                double cA = dpp_movd<0x142>(znA); // row_bcast15
                double upA = ((t & 15) == 0) ? cA : aA;
                nb2A = nb1A;
                nb1A = (lane == 0) ? rvcA[k] : upA;
                double aB = dpp_movd<0x111>(znB);
                double cB = dpp_movd<0x142>(znB);
                double upB = ((t & 15) == 0) ? cB : aB;
                nb2B = nb1B;
                nb1B = (lane == 0) ? rvcB[k] : upB;
            }

            if (lane == 63) {                     // offsets for ring readers
                ringo[0][w][g & 1] = offA;
                ringo[1][w][g & 1] = offB;
            }

            // Per-wave exact power-of-2 rescale, DPP max-reduce (no LDS).
            int eA = (int)((__double_as_longlong(curA) >> 52) & 0x7FF);
            int eB = (int)((__double_as_longlong(curB) >> 52) & 0x7FF);
            eA = wave_max_i(eA);
            eB = wave_max_i(eB);
            if (eA > 0) {
                int sh = 1023 - eA;
                int c1 = min(max(sh, -1022), 1022);
                int c2 = min(max(sh - c1, -1022), 1022);
                double f1 = pow2d(c1), f2 = pow2d(c2);
                curA = (curA * f1) * f2;
                nb1A = (nb1A * f1) * f2;
                nb2A = (nb2A * f1) * f2;
                offA += sh;
            }
            if (eB > 0) {
                int sh = 1023 - eB;
                int c1 = min(max(sh, -1022), 1022);
                int c2 = min(max(sh - c1, -1022), 1022);
                double f1 = pow2d(c1), f2 = pow2d(c2);
                curB = (curB * f1) * f2;
                nb1B = (nb1B * f1) * f2;
                nb2B = (nb2B * f1) * f2;
                offB += sh;
            }
        }

        d0 += K;

        // Epoch bottom: step factors for the next epoch (hidden pre-barrier).
        compute_k2(d0, t, spA, cgA, spB, cgB, k2A, k2B);

        __syncthreads();
    }

    // Thread 1023: res = Z of R[1023,1023] at res_off (exact snapshot).
    if (t == TPB - 1) {
        double RA = ((double)res_offA - log2(resA)) * LN2D;
        double RB = ((double)res_offB - log2(resB)) * LN2D;
        atomicAdd(out, (float)((RA + RB) * (1.0 / 64.0)));
    }
}

extern "C" void kernel_launch(void* const* d_in, const int* in_sizes, int n_in,
                              void* d_out, int out_size, void* d_ws, size_t ws_size,
                              hipStream_t stream) {
    const float2* snake   = (const float2*)d_in[0];
    const float2* contour = (const float2*)d_in[1];
    float* out = (float*)d_out;
    // Harness re-poisons d_out to 0xAA before every timed launch.
    hipMemsetAsync(out, 0, sizeof(float), stream);
    dtw_kernel<<<32, TPB, 0, stream>>>(snake, contour, out);
}

// Round 10
// 821.651 us; speedup vs baseline: 1.0701x; 1.0701x over previous
//
#include <hip/hip_runtime.h>

// Soft-DTW (gamma=1), batched 64 x (1024 vs 1024, 2-D points).
//
// === R10: use all 256 CUs ===
// R8/R9 counters decoded: OccupancyPercent/VALUBusy are DEVICE-WIDE averages
// (12.5% occ = 1024 waves/8192 slots). Active-CU VALUBusy was ~74-81% in
// every fast version, and R9 (32 blocks) scaled inverse-linearly vs R8 (64
// blocks): the kernel is ISSUE-BOUND on however many CUs it occupies, and it
// occupied only 64/256. This version splits each batch's 1024 rows across
// PARTS=4 blocks x 4 waves (256 threads) -> 256 blocks = every CU.
//
// Global 16-wave skew pipeline is UNCHANGED from R8 (verified absmax 0.0):
// global wave w = part*4 + wl; wave w runs K=8 diagonals behind wave w-1; at
// epoch g, step k it computes diag dk = 8g+k+2-8w; one __syncthreads per
// epoch inside each block. Per-wave arithmetic is bit-identical to R8:
// exp2-domain Z = 2^(off - R*log2e), chain = add+add+mul (f64) + DPP shift,
// zero transcendentals on-chain; per-wave power-of-2 rescale per epoch (DPP
// max-reduce, pure VALU); lane-0 neighbor values converted by exact
// 2^(off-oin) two-stage factors.
//
// Only the TRANSPORT at the 3 intra-batch block boundaries changes:
//  - intra-block (wl>0): LDS ring, parity double-buffer (as R8).
//  - cross-block (wl==0, part>0): 16-slot global ring in d_ws. Writer
//    (wl=3, lane 63) publishes {8 raw f64 boundary values, off} to slot
//    g&15 with relaxed agent stores, then flag=g with RELEASE agent store.
//    Reader polls flag >= g at EPOCH BOTTOM (prefetch for epoch g+1 ->
//    latency hidden under the barrier), loads raw values with relaxed agent
//    loads, converts at top with the same 2^(off-oin) ops as R8.
//  - Writer lifetime: writer w-1 publishes only while ITS overlap holds,
//    i.e. epochs <= WLAST = 9*(w-1)+135. Reader epochs needing g-1 > WLAST
//    zero-fill rvc (those values feed only inactive cells -- exactly R8's
//    stale-slot semantics, where any finite value was unused). This also
//    avoids polling a flag that will never advance (hang).
//  - flags initialized to -1 via hipMemsetAsync(d_ws, 0xFF) per launch.
//    Slot-overwrite window = 16 epochs of reader lag (~many us) >> scheduler
//    noise with 1 block/CU. Blocks are part-major (parts of a batch 64
//    apart -> same XCD under round-robin -> handoff stays in-XCD L2);
//    correctness does not depend on placement (agent-scope atomics).
// Deadlock-free: dependency is one-directional (part 0 waits on nobody and
// dispatches first); all 256 small blocks are co-resident.
//
// Final: R = (res_off - log2(res)) * ln2 from the (row 1023, d=2046) cell
// snapshot; mean over batch via one atomicAdd per batch (part 3, t 255).

#define N 1024
#define PARTS 4
#define TPB 256
#define WPB 4                                  // waves per block
#define NW_G (PARTS * WPB)                     // 16 global waves
#define K 8                                    // diagonals per epoch
#define TOTAL (2 * N - 3 + (NW_G - 1) * K)     // 2045 + 120 = 2165 steps
#define NGRP ((TOTAL + K - 1) / K)             // 271 epochs
#define SLOTS 16                               // cross-block ring depth
#define NBND (PARTS - 1)                       // boundaries per batch
#define L2E 1.442695040888963f
#define LN2D 0.6931471805599453

// workspace: vals[64][NBND][SLOTS][9] doubles, then flags[64][NBND] int64
#define VALS_DBL (64 * NBND * SLOTS * 9)
#define WS_BYTES (VALS_DBL * 8 + 64 * NBND * 8)

__device__ __forceinline__ float sqdist2(float2 a, float2 b) {
    float dx = a.x - b.x;
    float dy = a.y - b.y;
    return dx * dx + dy * dy;
}

// 64-bit DPP move (two 32-bit halves, same lane pattern; invalid lanes -> 0).
template <int CTRL>
__device__ __forceinline__ double dpp_movd(double src) {
    long long s = __double_as_longlong(src);
    int lo = __builtin_amdgcn_update_dpp(0, (int)(s & 0xffffffffLL),
                                         CTRL, 0xF, 0xF, false);
    int hi = __builtin_amdgcn_update_dpp(0, (int)(s >> 32),
                                         CTRL, 0xF, 0xF, false);
    return __longlong_as_double(((long long)hi << 32) | (unsigned int)lo);
}

template <int CTRL>
__device__ __forceinline__ int dpp_maxstep(int x) {
    int s = __builtin_amdgcn_update_dpp(0, x, CTRL, 0xF, 0xF, false);
    return max(x, s);
}

// Full 64-lane max of a nonneg int, pure VALU (no LDS); result wave-uniform.
__device__ __forceinline__ int wave_max_i(int x) {
    x = dpp_maxstep<0x111>(x);   // row_shr:1
    x = dpp_maxstep<0x112>(x);   // row_shr:2
    x = dpp_maxstep<0x114>(x);   // row_shr:4
    x = dpp_maxstep<0x118>(x);   // row_shr:8
    x = dpp_maxstep<0x142>(x);   // row_bcast15
    x = dpp_maxstep<0x143>(x);   // row_bcast31
    return __builtin_amdgcn_readlane(x, 63);
}

// exact 2^s as double for s in [-1022, 1023]
__device__ __forceinline__ double pow2d(int s) {
    return __longlong_as_double((long long)(1023 + s) << 52);
}

// k2[k] = act ? 2^(-cost*log2e) : 0 for the K diagonals starting at d0.
__device__ __forceinline__ void compute_k2(int d0, int i, float2 sp,
                                           const float2* cg, double* k2) {
    #pragma unroll
    for (int k = 0; k < K; ++k) {
        const unsigned u = (unsigned)(d0 + k - i);
        const bool act = u < (unsigned)N;
        float2 c = cg[u & (N - 1)];          // wrapped -> in-bounds garbage
        float dx = sp.x - c.x, dy = sp.y - c.y;
        float e = __builtin_amdgcn_exp2f((dx * dx + dy * dy) * (-L2E));
        k2[k] = act ? (double)e : 0.0;
    }
}

__global__ __launch_bounds__(TPB) void dtw_kernel(
    const float2* __restrict__ snake,
    const float2* __restrict__ contour,
    float* __restrict__ out,
    double* __restrict__ wsv,
    long long* __restrict__ wsf)
{
    const int t    = threadIdx.x;
    const int lane = t & 63;
    const int wl   = t >> 6;                 // local wave 0..3
    const int part = blockIdx.x >> 6;        // part-major: writers first
    const int b    = blockIdx.x & 63;        // batch
    const int w    = part * WPB + wl;        // global wave 0..15
    const int i    = (w << 6) + lane;        // global DP row

    __shared__ double ringv[WPB][2][K];      // intra-block boundary ring
    __shared__ int    ringo[WPB][2];
    __shared__ float  initvals[3];           // R0[0], R1[0], R1[1]

    const float2* sg = snake   + (size_t)b * N;
    const float2* cg = contour + (size_t)b * N;
    const float2 sp = sg[i];                 // snake point: register-resident

    if (t < WPB * 2 * K) ((double*)ringv)[t] = 0.0;   // Z(INF) = 0
    if (t < WPB * 2)     ((int*)ringo)[t] = 0;
    if (part == 0 && t == 0) {
        // Diagonals 0 and 1 (reference `init`):
        float2 s0 = sg[0], s1 = sg[1], c0 = cg[0], c1 = cg[1];
        float d00 = sqdist2(s0, c0);
        initvals[0] = d00;
        initvals[1] = sqdist2(s0, c1) + d00;
        initvals[2] = sqdist2(s1, c0) + d00;
    }
    __syncthreads();

    // Z-state entering the wave's first executed step (off = 0):
    double cur = 0.0, nb1 = 0.0, nb2 = 0.0;
    int off = 0;
    bool adopted = (w == 0);
    if (part == 0) {
        if (t == 0) {
            cur = (double)__builtin_amdgcn_exp2f(-L2E * initvals[1]);
        } else if (t == 1) {
            cur = (double)__builtin_amdgcn_exp2f(-L2E * initvals[2]);
            nb1 = (double)__builtin_amdgcn_exp2f(-L2E * initvals[1]);
            nb2 = (double)__builtin_amdgcn_exp2f(-L2E * initvals[0]);
        } else if (t == 2) {
            nb1 = (double)__builtin_amdgcn_exp2f(-L2E * initvals[2]);
        }
    }

    double res = 1.0;                        // final-cell snapshot (my row)
    int res_off = 0;

    const int lo = (w == 0) ? 2 : (64 * w - 1);   // -1 pre-step seeds nb1
    const int hi = 64 * w + 63 + (N - 1);
    const int WLAST = 9 * (w - 1) + 135;          // writer's last publish
    int d0 = 2 - K * w;

    double k2[K], rvc[K], wb[K];
    #pragma unroll
    for (int k = 0; k < K; ++k) rvc[k] = 0.0;
    double vr_p[9];                          // cross-block prefetch (lane 0)
    #pragma unroll
    for (int k = 0; k < 9; ++k) vr_p[k] = 0.0;

    const long long* vin =
        (const long long*)(wsv + ((size_t)b * NBND + (part - 1)) * SLOTS * 9);
    long long* vout =
        (long long*)(wsv + ((size_t)b * NBND + part) * SLOTS * 9);
    const long long* fin = wsf + (b * NBND + (part - 1));
    long long* fout = wsf + (b * NBND + part);

    compute_k2(d0, i, sp, cg, k2);           // epoch 0 factors
    // (iteration-0 cross-block read never happens: overlap false for w>0,wl==0)

    for (int g = 0; g < NGRP; ++g) {
        const bool overlap = (d0 <= hi) && (d0 + (K - 1) >= lo);
        if (overlap) {
            if (w > 0) {
                int oin;
                if (wl > 0) {
                    const int p = (g ^ 1) & 1;
                    oin = ringo[wl - 1][p];                // all lanes (LDS)
                    if (!adopted) { off = oin; adopted = true; }
                    if (lane == 0) {
                        int dl = off - oin;
                        int c1 = min(max(dl, -1022), 1022);
                        int c2 = min(max(dl - c1, -1022), 1022);
                        double f1 = pow2d(c1), f2 = pow2d(c2);
                        const double* q = &ringv[wl - 1][p][0];
                        #pragma unroll
                        for (int k = 0; k < K; ++k)
                            rvc[k] = (q[k] * f1) * f2;
                    }
                } else {
                    int tmp = 0;
                    if (lane == 0) tmp = (int)vr_p[8];
                    oin = __builtin_amdgcn_readlane(tmp, 0);  // broadcast
                    if (!adopted) { off = oin; adopted = true; }
                    if (lane == 0) {
                        int dl = off - oin;
                        int c1 = min(max(dl, -1022), 1022);
                        int c2 = min(max(dl - c1, -1022), 1022);
                        double f1 = pow2d(c1), f2 = pow2d(c2);
                        #pragma unroll
                        for (int k = 0; k < K; ++k)
                            rvc[k] = (vr_p[k] * f1) * f2;
                    }
                }
            }

            const int kres = (i + N - 1) - d0;   // step of my row's last cell

            // The chain: add+add+mul (f64) + DPP + selects per step.
            #pragma unroll
            for (int k = 0; k < K; ++k) {
                double zn = k2[k] * ((nb2 + nb1) + cur);
                wb[k] = zn;
                if (k == kres) { res = zn; res_off = off; }
                cur = zn;
                double a  = dpp_movd<0x111>(zn);   // row_shr:1
                double bc = dpp_movd<0x142>(zn);   // row_bcast15
                double up = ((lane & 15) == 0) ? bc : a;
                nb2 = nb1;
                nb1 = (lane == 0) ? rvc[k] : up;
            }

            // Boundary publish (epoch-end, raw values at pre-rescale off).
            if (lane == 63) {
                if (wl < WPB - 1) {
                    #pragma unroll
                    for (int k = 0; k < K; ++k) ringv[wl][g & 1][k] = wb[k];
                    ringo[wl][g & 1] = off;
                } else if (part < PARTS - 1) {
                    long long* q = vout + (size_t)(g & (SLOTS - 1)) * 9;
                    #pragma unroll
                    for (int k = 0; k < K; ++k)
                        __hip_atomic_store(q + k, __double_as_longlong(wb[k]),
                                           __ATOMIC_RELAXED,
                                           __HIP_MEMORY_SCOPE_AGENT);
                    __hip_atomic_store(q + 8, __double_as_longlong((double)off),
                                       __ATOMIC_RELAXED,
                                       __HIP_MEMORY_SCOPE_AGENT);
                    __hip_atomic_store(fout, (long long)g, __ATOMIC_RELEASE,
                                       __HIP_MEMORY_SCOPE_AGENT);
                }
            }

            // Per-wave exact power-of-2 rescale (DPP max-reduce, no LDS).
            int e = (int)((__double_as_longlong(cur) >> 52) & 0x7FF);
            e = wave_max_i(e);
            if (e > 0) {
                int sh = 1023 - e;
                int c1 = min(max(sh, -1022), 1022);
                int c2 = min(max(sh - c1, -1022), 1022);
                double f1 = pow2d(c1), f2 = pow2d(c2);
                cur = (cur * f1) * f2;
                nb1 = (nb1 * f1) * f2;
                nb2 = (nb2 * f1) * f2;
                off += sh;
            }
        }

        d0 += K;
        compute_k2(d0, i, sp, cg, k2);       // next-epoch factors

        // Cross-block PREFETCH for epoch g+1 (poll+read at epoch bottom ->
        // handoff latency hides under the barrier).
        if (wl == 0 && w > 0) {
            const bool nov = (d0 <= hi) && (d0 + (K - 1) >= lo);
            if (nov && lane == 0) {
                const int need = g;           // = (g+1) - 1
                if (need > WLAST) {
                    // Writer finished: values feed only inactive cells.
                    #pragma unroll
                    for (int k = 0; k < K; ++k) vr_p[k] = 0.0;
                    vr_p[8] = (double)off;    // zeros are offset-immune
                } else {
                    while (__hip_atomic_load(fin, __ATOMIC_ACQUIRE,
                                             __HIP_MEMORY_SCOPE_AGENT)
                           < (long long)need)
                        __builtin_amdgcn_s_sleep(1);
                    const long long* q = vin + (size_t)(need & (SLOTS - 1)) * 9;
                    #pragma unroll
                    for (int k = 0; k < 9; ++k)
                        vr_p[k] = __longlong_as_double(
                            __hip_atomic_load(q + k, __ATOMIC_RELAXED,
                                              __HIP_MEMORY_SCOPE_AGENT));
                }
            }
        }

        __syncthreads();
    }

    // Global row 1023 lives in part 3, t 255: res = Z of R[1023,1023].
    if (part == PARTS - 1 && t == TPB - 1) {
        double R = ((double)res_off - log2(res)) * LN2D;
        atomicAdd(out, (float)(R * (1.0 / 64.0)));
    }
}

extern "C" void kernel_launch(void* const* d_in, const int* in_sizes, int n_in,
                              void* d_out, int out_size, void* d_ws, size_t ws_size,
                              hipStream_t stream) {
    const float2* snake   = (const float2*)d_in[0];
    const float2* contour = (const float2*)d_in[1];
    float* out = (float*)d_out;
    // Harness re-poisons d_out to 0xAA before every timed launch.
    hipMemsetAsync(out, 0, sizeof(float), stream);
    // Cross-block flags must start at -1 (0xFF...) every launch.
    hipMemsetAsync(d_ws, 0xFF, WS_BYTES, stream);
    double* wsv = (double*)d_ws;
    long long* wsf = (long long*)((char*)d_ws + (size_t)VALS_DBL * 8);
    dtw_kernel<<<PARTS * 64, TPB, 0, stream>>>(snake, contour, out, wsv, wsf);
}

// Round 11
// 389.984 us; speedup vs baseline: 2.2547x; 2.1069x over previous
//
#include <hip/hip_runtime.h>

// Soft-DTW (gamma=1), batched 64 x (1024 vs 1024, 2-D points).
//
// === R11: all 256 CUs, cache-clean cross-block handoff, K=16 ===
// R10 (PARTS=4, acquire/release agent atomics) was correct but slow (771us):
// FETCH 0.55->4.3MB, WRITE 2KB->8.2MB revealed the cause -- on gfx950,
// ACQUIRE emits L1/L2 invalidates and RELEASE emits L2 writebacks (per-XCD
// L2 is non-coherent), and the reader's per-epoch acquire POLL LOOP in 192
// blocks thrashed every XCD's caches device-wide. Fix:
//  - cross-block traffic uses RELAXED agent-scope atomics only (sc1 path:
//    coherent at the LLC, NO cache-maintenance instructions). Ordering:
//    writer stores 17 values relaxed -> s_waitcnt vmcnt(0) -> relaxed flag
//    store. Reader polls relaxed flag (signed; init -1 via 0xFF memset) ->
//    compiler barrier -> relaxed value loads (issued after the poll branch).
//    Slot-overwrite safety: all blocks run the same epoch loop in wall
//    lockstep; slot ring depth 8 epochs >> inter-part lag (R10-validated).
//  - K=8 -> 16 diagonals/epoch: halves the per-step share of per-epoch fixed
//    costs (handoff ~800cyc, rescale, barrier, LDS ring). Skew cost: 15*16 =
//    240 extra steps (+9%); NGRP 271 -> 143.
//
// Everything else is the R10/R8-verified structure (absmax 0.0): 256 blocks
// = 64 batches x PARTS=4 parts x 4 waves; global wave w = part*4+wl runs K
// diagonals behind wave w-1; exp2-domain Z = 2^(off - R*log2e); chain =
// add+add+mul (f64) + DPP shift, zero transcendentals on-chain; per-wave
// power-of-2 rescale per epoch (DPP max-reduce); lane-0 neighbor values
// converted by exact 2^(off-oin); intra-block boundaries via LDS parity
// ring; final cell snapshotted at its own step; R = (off - log2(Z)) * ln2.

#define N 1024
#define PARTS 4
#define TPB 256
#define WPB 4                                  // waves per block
#define NW_G (PARTS * WPB)                     // 16 global waves
#define K 16                                   // diagonals per epoch
#define TOTAL (2 * N - 3 + (NW_G - 1) * K)     // 2045 + 240 = 2285 steps
#define NGRP ((TOTAL + K - 1) / K)             // 143 epochs
#define SLOTS 8                                // cross-block ring depth
#define NBND (PARTS - 1)                       // boundaries per batch
#define L2E 1.442695040888963f
#define LN2D 0.6931471805599453

// workspace: vals[64][NBND][SLOTS][K+1] int64, then flags[64][NBND] int64
#define VALS_LL (64 * NBND * SLOTS * (K + 1))
#define WS_BYTES (VALS_LL * 8 + 64 * NBND * 8)

__device__ __forceinline__ float sqdist2(float2 a, float2 b) {
    float dx = a.x - b.x;
    float dy = a.y - b.y;
    return dx * dx + dy * dy;
}

// 64-bit DPP move (two 32-bit halves, same lane pattern; invalid lanes -> 0).
template <int CTRL>
__device__ __forceinline__ double dpp_movd(double src) {
    long long s = __double_as_longlong(src);
    int lo = __builtin_amdgcn_update_dpp(0, (int)(s & 0xffffffffLL),
                                         CTRL, 0xF, 0xF, false);
    int hi = __builtin_amdgcn_update_dpp(0, (int)(s >> 32),
                                         CTRL, 0xF, 0xF, false);
    return __longlong_as_double(((long long)hi << 32) | (unsigned int)lo);
}

template <int CTRL>
__device__ __forceinline__ int dpp_maxstep(int x) {
    int s = __builtin_amdgcn_update_dpp(0, x, CTRL, 0xF, 0xF, false);
    return max(x, s);
}

// Full 64-lane max of a nonneg int, pure VALU (no LDS); result wave-uniform.
__device__ __forceinline__ int wave_max_i(int x) {
    x = dpp_maxstep<0x111>(x);   // row_shr:1
    x = dpp_maxstep<0x112>(x);   // row_shr:2
    x = dpp_maxstep<0x114>(x);   // row_shr:4
    x = dpp_maxstep<0x118>(x);   // row_shr:8
    x = dpp_maxstep<0x142>(x);   // row_bcast15
    x = dpp_maxstep<0x143>(x);   // row_bcast31
    return __builtin_amdgcn_readlane(x, 63);
}

// exact 2^s as double for s in [-1022, 1023]
__device__ __forceinline__ double pow2d(int s) {
    return __longlong_as_double((long long)(1023 + s) << 52);
}

// k2[k] = act ? 2^(-cost*log2e) : 0 for the K diagonals starting at d0.
__device__ __forceinline__ void compute_k2(int d0, int i, float2 sp,
                                           const float2* cg, double* k2) {
    #pragma unroll
    for (int k = 0; k < K; ++k) {
        const unsigned u = (unsigned)(d0 + k - i);
        const bool act = u < (unsigned)N;
        float2 c = cg[u & (N - 1)];          // wrapped -> in-bounds garbage
        float dx = sp.x - c.x, dy = sp.y - c.y;
        float e = __builtin_amdgcn_exp2f((dx * dx + dy * dy) * (-L2E));
        k2[k] = act ? (double)e : 0.0;
    }
}

__global__ __launch_bounds__(TPB) void dtw_kernel(
    const float2* __restrict__ snake,
    const float2* __restrict__ contour,
    float* __restrict__ out,
    long long* __restrict__ wsv,
    long long* __restrict__ wsf)
{
    const int t    = threadIdx.x;
    const int lane = t & 63;
    const int wl   = t >> 6;                 // local wave 0..3
    const int part = blockIdx.x >> 6;        // part-major: writers first
    const int b    = blockIdx.x & 63;        // batch
    const int w    = part * WPB + wl;        // global wave 0..15
    const int i    = (w << 6) + lane;        // global DP row

    __shared__ double ringv[WPB][2][K];      // intra-block boundary ring
    __shared__ int    ringo[WPB][2];
    __shared__ float  initvals[3];           // R0[0], R1[0], R1[1]

    const float2* sg = snake   + (size_t)b * N;
    const float2* cg = contour + (size_t)b * N;
    const float2 sp = sg[i];                 // snake point: register-resident

    if (t < WPB * 2 * K) ((double*)ringv)[t] = 0.0;   // Z(INF) = 0
    if (t < WPB * 2)     ((int*)ringo)[t] = 0;
    if (part == 0 && t == 0) {
        // Diagonals 0 and 1 (reference `init`):
        float2 s0 = sg[0], s1 = sg[1], c0 = cg[0], c1 = cg[1];
        float d00 = sqdist2(s0, c0);
        initvals[0] = d00;
        initvals[1] = sqdist2(s0, c1) + d00;
        initvals[2] = sqdist2(s1, c0) + d00;
    }
    __syncthreads();

    // Z-state entering the wave's first executed step (off = 0):
    double cur = 0.0, nb1 = 0.0, nb2 = 0.0;
    int off = 0;
    bool adopted = (w == 0);
    if (part == 0) {
        if (t == 0) {
            cur = (double)__builtin_amdgcn_exp2f(-L2E * initvals[1]);
        } else if (t == 1) {
            cur = (double)__builtin_amdgcn_exp2f(-L2E * initvals[2]);
            nb1 = (double)__builtin_amdgcn_exp2f(-L2E * initvals[1]);
            nb2 = (double)__builtin_amdgcn_exp2f(-L2E * initvals[0]);
        } else if (t == 2) {
            nb1 = (double)__builtin_amdgcn_exp2f(-L2E * initvals[2]);
        }
    }

    double res = 1.0;                        // final-cell snapshot (my row)
    int res_off = 0;

    const int lo = (w == 0) ? 2 : (64 * w - 1);   // -1 pre-step seeds nb1
    const int hi = 64 * w + 63 + (N - 1);
    // Writer (wave w-1) last publishing epoch: max g with d0_{w-1}(g) <= hi_{w-1}.
    const int WLAST = (w > 0) ? ((64 * (w - 1) + 1084) / K + (w - 1)) : 0;
    int d0 = 2 - K * w;

    double k2[K], rvc[K], wb[K];
    #pragma unroll
    for (int k = 0; k < K; ++k) rvc[k] = 0.0;
    double vr_p[K];                          // cross-block prefetch (lane 0)
    #pragma unroll
    for (int k = 0; k < K; ++k) vr_p[k] = 0.0;
    int oin_p = 0;

    const long long* vin =
        wsv + ((size_t)b * NBND + (part - 1)) * SLOTS * (K + 1);
    long long* vout =
        wsv + ((size_t)b * NBND + part) * SLOTS * (K + 1);
    const long long* fin = wsf + (b * NBND + (part - 1));
    long long* fout = wsf + (b * NBND + part);

    compute_k2(d0, i, sp, cg, k2);           // epoch 0 factors
    // (epoch-0 cross-block read never happens: overlap false for w>0, wl==0)

    for (int g = 0; g < NGRP; ++g) {
        const bool overlap = (d0 <= hi) && (d0 + (K - 1) >= lo);
        if (overlap) {
            if (w > 0) {
                int oin;
                if (wl > 0) {
                    const int p = (g ^ 1) & 1;
                    oin = ringo[wl - 1][p];                // all lanes (LDS)
                    if (!adopted) { off = oin; adopted = true; }
                    if (lane == 0) {
                        int dl = off - oin;
                        int c1 = min(max(dl, -1022), 1022);
                        int c2 = min(max(dl - c1, -1022), 1022);
                        double f1 = pow2d(c1), f2 = pow2d(c2);
                        const double* q = &ringv[wl - 1][p][0];
                        #pragma unroll
                        for (int k = 0; k < K; ++k)
                            rvc[k] = (q[k] * f1) * f2;
                    }
                } else {
                    int tmp = (lane == 0) ? oin_p : 0;
                    oin = __builtin_amdgcn_readlane(tmp, 0);  // broadcast
                    if (!adopted) { off = oin; adopted = true; }
                    if (lane == 0) {
                        int dl = off - oin;
                        int c1 = min(max(dl, -1022), 1022);
                        int c2 = min(max(dl - c1, -1022), 1022);
                        double f1 = pow2d(c1), f2 = pow2d(c2);
                        #pragma unroll
                        for (int k = 0; k < K; ++k)
                            rvc[k] = (vr_p[k] * f1) * f2;
                    }
                }
            }

            const int kres = (i + N - 1) - d0;   // step of my row's last cell

            // The chain: add+add+mul (f64) + DPP + selects per step.
            #pragma unroll
            for (int k = 0; k < K; ++k) {
                double zn = k2[k] * ((nb2 + nb1) + cur);
                wb[k] = zn;
                if (k == kres) { res = zn; res_off = off; }
                cur = zn;
                double a  = dpp_movd<0x111>(zn);   // row_shr:1
                double bc = dpp_movd<0x142>(zn);   // row_bcast15
                double up = ((lane & 15) == 0) ? bc : a;
                nb2 = nb1;
                nb1 = (lane == 0) ? rvc[k] : up;
            }

            // Boundary publish (epoch-end, raw values at pre-rescale off).
            if (lane == 63) {
                if (wl < WPB - 1) {
                    #pragma unroll
                    for (int k = 0; k < K; ++k) ringv[wl][g & 1][k] = wb[k];
                    ringo[wl][g & 1] = off;
                } else if (part < PARTS - 1) {
                    // RELAXED agent stores (sc1: coherent at LLC, no cache
                    // maintenance). vmcnt(0) orders values before the flag.
                    long long* q = vout + (size_t)(g & (SLOTS - 1)) * (K + 1);
                    #pragma unroll
                    for (int k = 0; k < K; ++k)
                        __hip_atomic_store(q + k, __double_as_longlong(wb[k]),
                                           __ATOMIC_RELAXED,
                                           __HIP_MEMORY_SCOPE_AGENT);
                    __hip_atomic_store(q + K, (long long)off,
                                       __ATOMIC_RELAXED,
                                       __HIP_MEMORY_SCOPE_AGENT);
                    asm volatile("s_waitcnt vmcnt(0)" ::: "memory");
                    __hip_atomic_store(fout, (long long)g, __ATOMIC_RELAXED,
                                       __HIP_MEMORY_SCOPE_AGENT);
                }
            }

            // Per-wave exact power-of-2 rescale (DPP max-reduce, no LDS).
            int e = (int)((__double_as_longlong(cur) >> 52) & 0x7FF);
            e = wave_max_i(e);
            if (e > 0) {
                int sh = 1023 - e;
                int c1 = min(max(sh, -1022), 1022);
                int c2 = min(max(sh - c1, -1022), 1022);
                double f1 = pow2d(c1), f2 = pow2d(c2);
                cur = (cur * f1) * f2;
                nb1 = (nb1 * f1) * f2;
                nb2 = (nb2 * f1) * f2;
                off += sh;
            }
        }

        d0 += K;
        compute_k2(d0, i, sp, cg, k2);       // next-epoch factors

        // Cross-block PREFETCH for epoch g+1 (poll+read at epoch bottom ->
        // handoff latency hides under the barrier / epoch tail).
        if (wl == 0 && w > 0) {
            const bool nov = (d0 <= hi) && (d0 + (K - 1) >= lo);
            if (nov && lane == 0) {
                const int need = g;           // = (g+1) - 1
                if (need > WLAST) {
                    // Writer finished: values feed only inactive cells.
                    #pragma unroll
                    for (int k = 0; k < K; ++k) vr_p[k] = 0.0;
                    oin_p = off;              // zeros are offset-immune
                } else {
                    while (__hip_atomic_load(fin, __ATOMIC_RELAXED,
                                             __HIP_MEMORY_SCOPE_AGENT)
                           < (long long)need)
                        __builtin_amdgcn_s_sleep(2);
                    asm volatile("" ::: "memory");   // no hoist past poll
                    const long long* q =
                        vin + (size_t)(need & (SLOTS - 1)) * (K + 1);
                    #pragma unroll
                    for (int k = 0; k < K; ++k)
                        vr_p[k] = __longlong_as_double(
                            __hip_atomic_load(q + k, __ATOMIC_RELAXED,
                                              __HIP_MEMORY_SCOPE_AGENT));
                    oin_p = (int)__hip_atomic_load(q + K, __ATOMIC_RELAXED,
                                                   __HIP_MEMORY_SCOPE_AGENT);
                }
            }
        }

        __syncthreads();
    }

    // Global row 1023 lives in part 3, t 255: res = Z of R[1023,1023].
    if (part == PARTS - 1 && t == TPB - 1) {
        double R = ((double)res_off - log2(res)) * LN2D;
        atomicAdd(out, (float)(R * (1.0 / 64.0)));
    }
}

extern "C" void kernel_launch(void* const* d_in, const int* in_sizes, int n_in,
                              void* d_out, int out_size, void* d_ws, size_t ws_size,
                              hipStream_t stream) {
    const float2* snake   = (const float2*)d_in[0];
    const float2* contour = (const float2*)d_in[1];
    float* out = (float*)d_out;
    // Harness re-poisons d_out to 0xAA before every timed launch.
    hipMemsetAsync(out, 0, sizeof(float), stream);
    // Cross-block flags must start at -1 (0xFF...) every launch.
    hipMemsetAsync(d_ws, 0xFF, WS_BYTES, stream);
    long long* wsv = (long long*)d_ws;
    long long* wsf = (long long*)((char*)d_ws + (size_t)VALS_LL * 8);
    dtw_kernel<<<PARTS * 64, TPB, 0, stream>>>(snake, contour, out, wsv, wsf);
}